// Round 1
// baseline (3523.186 us; speedup 1.0000x reference)
//
#include <hip/hip_runtime.h>

#define BB 16
#define PP 2048
#define NN 32768   // BB*PP
#define KK 16
#define EPSF 1e-5f

// ============================ 3-D KNN ============================
__global__ void knn3_kernel(const float* __restrict__ x, int* __restrict__ idx) {
    __shared__ float sp[PP * 3];
    __shared__ float sd[PP];
    __shared__ float rv[4];
    __shared__ int   ri[4];
    const int b = blockIdx.y, q = blockIdx.x, tid = threadIdx.x;
    const float* xc = x + (size_t)b * PP * 3;
    for (int i = tid; i < PP * 3; i += 256) sp[i] = xc[i];
    __syncthreads();
    const float qx = sp[q * 3 + 0], qy = sp[q * 3 + 1], qz = sp[q * 3 + 2];
    const float sqQ = qx * qx + qy * qy + qz * qz;
    for (int c = tid; c < PP; c += 256) {
        float cx = sp[c * 3 + 0], cy = sp[c * 3 + 1], cz = sp[c * 3 + 2];
        float sqC = cx * cx + cy * cy + cz * cz;
        float d = sqQ + sqC - 2.f * (qx * cx + qy * cy + qz * cz);
        if (c == q) d += 1e10f;
        sd[c] = d;
    }
    __syncthreads();
    int* orow = idx + ((size_t)b * PP + q) * KK;
    for (int it = 0; it < KK; ++it) {
        float bv = 3.4e38f; int bi = PP;
        for (int c = tid; c < PP; c += 256) {
            float v = sd[c];
            if (v < bv) { bv = v; bi = c; }
        }
        #pragma unroll
        for (int off = 32; off; off >>= 1) {
            float v2 = __shfl_down(bv, off);
            int   i2 = __shfl_down(bi, off);
            if (v2 < bv || (v2 == bv && i2 < bi)) { bv = v2; bi = i2; }
        }
        if ((tid & 63) == 0) { rv[tid >> 6] = bv; ri[tid >> 6] = bi; }
        __syncthreads();
        if (tid == 0) {
            float fv = rv[0]; int fi = ri[0];
            for (int w2 = 1; w2 < 4; ++w2)
                if (rv[w2] < fv || (rv[w2] == fv && ri[w2] < fi)) { fv = rv[w2]; fi = ri[w2]; }
            orow[it] = b * PP + fi;   // global row index
            sd[fi] = 3.4e38f;
        }
        __syncthreads();
    }
}

// ============================ local covariance -> h0[N,12] ============================
__global__ void cov_kernel(const float* __restrict__ x, const int* __restrict__ idx,
                           float* __restrict__ h0) {
    int p = blockIdx.x * 256 + threadIdx.x;
    if (p >= NN) return;
    const int* ip = idx + (size_t)p * KK;
    float nx[KK], ny[KK], nz[KK];
    float mx = 0.f, my = 0.f, mz = 0.f;
    #pragma unroll
    for (int k = 0; k < KK; ++k) {
        int j = ip[k];
        float a = x[j * 3 + 0], b2 = x[j * 3 + 1], c2 = x[j * 3 + 2];
        nx[k] = a; ny[k] = b2; nz[k] = c2;
        mx += a; my += b2; mz += c2;
    }
    mx *= (1.f / KK); my *= (1.f / KK); mz *= (1.f / KK);
    float cxx = 0, cxy = 0, cxz = 0, cyy = 0, cyz = 0, czz = 0;
    #pragma unroll
    for (int k = 0; k < KK; ++k) {
        float a = nx[k] - mx, b2 = ny[k] - my, c2 = nz[k] - mz;
        cxx += a * a;  cxy += a * b2;  cxz += a * c2;
        cyy += b2 * b2; cyz += b2 * c2; czz += c2 * c2;
    }
    const float s = 1.f / KK;
    float* o = h0 + (size_t)p * 12;
    o[0] = x[p * 3 + 0]; o[1] = x[p * 3 + 1]; o[2] = x[p * 3 + 2];
    o[3] = cxx * s; o[4]  = cxy * s; o[5]  = cxz * s;
    o[6] = cxy * s; o[7]  = cyy * s; o[8]  = cyz * s;
    o[9] = cxz * s; o[10] = cyz * s; o[11] = czz * s;
}

// ============================ tiled GEMM: C[M,Nc] = A[M,K] @ W[K,Nc] + bias ============================
// grid: (Nc/64, M/64), block 256. Handles K not multiple of 16 via zero-pad guard.
__global__ void gemm_nn_bias_kernel(const float* __restrict__ A, const float* __restrict__ W,
                                    const float* __restrict__ bias, float* __restrict__ C,
                                    int K, int Nc) {
    __shared__ float As[16][68];
    __shared__ float Ws[16][68];
    const int tid = threadIdx.x;
    const int m0 = blockIdx.y * 64, n0 = blockIdx.x * 64;
    const int tx = tid & 15, ty = tid >> 4;
    float acc[4][4] = {};
    for (int k0 = 0; k0 < K; k0 += 16) {
        {
            int kk = tid & 15, mp0 = tid >> 4;
            #pragma unroll
            for (int i = 0; i < 4; ++i) {
                int mp = mp0 + i * 16;
                float v = 0.f;
                if (k0 + kk < K) v = A[(size_t)(m0 + mp) * K + k0 + kk];
                As[kk][mp] = v;
            }
            int nn = tid & 63, kb = tid >> 6;
            #pragma unroll
            for (int i = 0; i < 4; ++i) {
                int kk3 = kb + i * 4;
                float v = 0.f;
                if (k0 + kk3 < K) v = W[(size_t)(k0 + kk3) * Nc + n0 + nn];
                Ws[kk3][nn] = v;
            }
        }
        __syncthreads();
        #pragma unroll
        for (int kk = 0; kk < 16; ++kk) {
            float4 a4 = *(const float4*)&As[kk][ty * 4];
            float4 b4 = *(const float4*)&Ws[kk][tx * 4];
            float av[4] = {a4.x, a4.y, a4.z, a4.w};
            float bv[4] = {b4.x, b4.y, b4.z, b4.w};
            #pragma unroll
            for (int i = 0; i < 4; ++i)
                #pragma unroll
                for (int j = 0; j < 4; ++j)
                    acc[i][j] = fmaf(av[i], bv[j], acc[i][j]);
        }
        __syncthreads();
    }
    float4 bb = *(const float4*)&bias[n0 + tx * 4];
    float bvv[4] = {bb.x, bb.y, bb.z, bb.w};
    #pragma unroll
    for (int i = 0; i < 4; ++i) {
        int m = m0 + ty * 4 + i;
        float4 r;
        r.x = acc[i][0] + bvv[0]; r.y = acc[i][1] + bvv[1];
        r.z = acc[i][2] + bvv[2]; r.w = acc[i][3] + bvv[3];
        *(float4*)&C[(size_t)m * Nc + n0 + tx * 4] = r;
    }
}

// ============================ gram: G[b, p-p0, q] = f_b[p,:] . f_b[q,:] ============================
// grid: (PP/64, QS/64, BB), block 256
__global__ void gram_kernel(const float* __restrict__ f, float* __restrict__ G,
                            int D, int p0, int QS) {
    __shared__ float As[16][68];
    __shared__ float Bs[16][68];
    const int b = blockIdx.z, tid = threadIdx.x;
    const int pm0 = p0 + blockIdx.y * 64, qn0 = blockIdx.x * 64;
    const float* fc = f + (size_t)b * PP * D;
    const int tx = tid & 15, ty = tid >> 4;
    float acc[4][4] = {};
    for (int k0 = 0; k0 < D; k0 += 16) {
        int kk = tid & 15, r0 = tid >> 4;
        #pragma unroll
        for (int i = 0; i < 4; ++i) {
            As[kk][r0 + i * 16] = fc[(size_t)(pm0 + r0 + i * 16) * D + k0 + kk];
            Bs[kk][r0 + i * 16] = fc[(size_t)(qn0 + r0 + i * 16) * D + k0 + kk];
        }
        __syncthreads();
        #pragma unroll
        for (int kk2 = 0; kk2 < 16; ++kk2) {
            float4 a4 = *(const float4*)&As[kk2][ty * 4];
            float4 b4 = *(const float4*)&Bs[kk2][tx * 4];
            float av[4] = {a4.x, a4.y, a4.z, a4.w};
            float bv[4] = {b4.x, b4.y, b4.z, b4.w};
            #pragma unroll
            for (int i = 0; i < 4; ++i)
                #pragma unroll
                for (int j = 0; j < 4; ++j)
                    acc[i][j] = fmaf(av[i], bv[j], acc[i][j]);
        }
        __syncthreads();
    }
    float* Gb = G + ((size_t)b * QS + (size_t)(pm0 - p0)) * PP;
    #pragma unroll
    for (int i = 0; i < 4; ++i) {
        float4 r = {acc[i][0], acc[i][1], acc[i][2], acc[i][3]};
        *(float4*)&Gb[(size_t)(ty * 4 + i) * PP + qn0 + tx * 4] = r;
    }
}

// ============================ top-16 selection from gram row ============================
// grid: (QS, BB), block 256
__global__ void knn_sel_kernel(const float* __restrict__ G, const float* __restrict__ sq,
                               int* __restrict__ idx, int p0, int QS) {
    __shared__ float sd[PP];
    __shared__ float rv[4];
    __shared__ int   ri[4];
    const int b = blockIdx.y, ql = p0 + blockIdx.x, tid = threadIdx.x;
    const float* Gr = G + ((size_t)b * QS + blockIdx.x) * PP;
    const float* sqc = sq + (size_t)b * PP;
    const float sqQ = sqc[ql];
    for (int c = tid; c < PP; c += 256) {
        float d = sqQ + sqc[c] - 2.f * Gr[c];
        if (c == ql) d += 1e10f;
        sd[c] = d;
    }
    __syncthreads();
    int* orow = idx + ((size_t)b * PP + ql) * KK;
    for (int it = 0; it < KK; ++it) {
        float bv = 3.4e38f; int bi = PP;
        for (int c = tid; c < PP; c += 256) {
            float v = sd[c];
            if (v < bv) { bv = v; bi = c; }
        }
        #pragma unroll
        for (int off = 32; off; off >>= 1) {
            float v2 = __shfl_down(bv, off);
            int   i2 = __shfl_down(bi, off);
            if (v2 < bv || (v2 == bv && i2 < bi)) { bv = v2; bi = i2; }
        }
        if ((tid & 63) == 0) { rv[tid >> 6] = bv; ri[tid >> 6] = bi; }
        __syncthreads();
        if (tid == 0) {
            float fv = rv[0]; int fi = ri[0];
            for (int w2 = 1; w2 < 4; ++w2)
                if (rv[w2] < fv || (rv[w2] == fv && ri[w2] < fi)) { fv = rv[w2]; fi = ri[w2]; }
            orow[it] = b * PP + fi;
            sd[fi] = 3.4e38f;
        }
        __syncthreads();
    }
}

// ============================ row sum of squares ============================
__global__ void row_sumsq_kernel(const float* __restrict__ f, float* __restrict__ sq, int D) {
    const int lane = threadIdx.x & 63;
    const int row = blockIdx.x * 4 + (threadIdx.x >> 6);
    const float* fr = f + (size_t)row * D;
    float s = 0.f;
    for (int d = lane; d < D; d += 64) { float v = fr[d]; s += v * v; }
    #pragma unroll
    for (int off = 32; off; off >>= 1) s += __shfl_down(s, off);
    if (lane == 0) sq[row] = s;
}

// ============================ gather + max over K neighbors ============================
__global__ void gathermax_kernel(const float* __restrict__ f, const int* __restrict__ idx,
                                 float* __restrict__ agg, int C) {
    size_t flat = (size_t)blockIdx.x * 256 + threadIdx.x;
    int c = (int)(flat % C);
    int n = (int)(flat / C);
    const int* ip = idx + (size_t)n * KK;
    float m = -3.4e38f;
    #pragma unroll
    for (int k = 0; k < KK; ++k) {
        float v = f[(size_t)ip[k] * C + c];
        m = fmaxf(m, v);
    }
    agg[flat] = m;
}

// ============================ BN stats (deterministic two-stage) ============================
__global__ void bn_part_kernel(const float* __restrict__ h, float* __restrict__ ps,
                               float* __restrict__ pss, int C) {
    const int blk = blockIdx.x, tid = threadIdx.x;
    const int rows = NN / 256;           // 128
    const int r0 = blk * rows;
    if (C <= 256) {
        int Gn = 256 / C;
        int sub = tid / C, c = tid % C;
        float s = 0.f, ss = 0.f;
        for (int r = r0 + sub; r < r0 + rows; r += Gn) {
            float v = h[(size_t)r * C + c];
            s += v; ss += v * v;
        }
        ps [((size_t)blk * Gn + sub) * C + c] = s;
        pss[((size_t)blk * Gn + sub) * C + c] = ss;
    } else {                             // C == 512
        for (int cb = 0; cb < C; cb += 256) {
            int c = cb + tid;
            float s = 0.f, ss = 0.f;
            for (int r = r0; r < r0 + rows; ++r) {
                float v = h[(size_t)r * C + c];
                s += v; ss += v * v;
            }
            ps [(size_t)blk * C + c] = s;
            pss[(size_t)blk * C + c] = ss;
        }
    }
}

__global__ void bn_final_kernel(const float* __restrict__ ps, const float* __restrict__ pss,
                                const float* __restrict__ g, const float* __restrict__ be,
                                float* __restrict__ a, float* __restrict__ bs, int C, int R) {
    int c = blockIdx.x * 256 + threadIdx.x;
    if (c >= C) return;
    float s = 0.f, ss = 0.f;
    for (int r = 0; r < R; ++r) { s += ps[(size_t)r * C + c]; ss += pss[(size_t)r * C + c]; }
    float m = s / (float)NN;
    float v = ss / (float)NN - m * m;
    float rstd = rsqrtf(v + EPSF);
    float aa = rstd * g[c];
    a[c] = aa;
    bs[c] = be[c] - m * aa;
}

__global__ void bn_apply_kernel(float* __restrict__ h, const float* __restrict__ a,
                                const float* __restrict__ bs, int C) {
    size_t flat = (size_t)blockIdx.x * 256 + threadIdx.x;
    int c = (int)(flat % C);
    float v = h[flat] * a[c] + bs[c];
    h[flat] = v > 0.f ? v : 0.f;
}

// ============================ segment max pool ============================
__global__ void segmax_kernel(const float* __restrict__ h, float* __restrict__ pooled) {
    const int b = blockIdx.x, chunk = blockIdx.y, tid = threadIdx.x;
    const int r0 = chunk * 128;
    for (int cb = 0; cb < 512; cb += 256) {
        int c = cb + tid;
        float m = 0.f;   // values are post-ReLU (>= 0)
        for (int r = r0; r < r0 + 128; ++r)
            m = fmaxf(m, h[((size_t)b * PP + r) * 512 + c]);
        atomicMax((int*)&pooled[b * 512 + c], __float_as_int(m));
    }
}

// ============================ small GEMM (M=16) ============================
__global__ void small_gemm_kernel(const float* __restrict__ A, const float* __restrict__ W,
                                  const float* __restrict__ bias, float* __restrict__ C,
                                  int K, int Nc) {
    int flat = blockIdx.x * 256 + threadIdx.x;
    int j = flat % Nc, i = flat / Nc;
    float s = bias[j];
    for (int k = 0; k < K; ++k) s = fmaf(A[(size_t)i * K + k], W[(size_t)k * Nc + j], s);
    C[flat] = s;
}

// ============================ BN over 16 rows + ReLU (in place) ============================
__global__ void bn16_kernel(float* __restrict__ h, const float* __restrict__ g,
                            const float* __restrict__ be) {
    int c = blockIdx.x * 256 + threadIdx.x;
    if (c >= 512) return;
    float s = 0.f, ss = 0.f;
    for (int r = 0; r < 16; ++r) { float v = h[r * 512 + c]; s += v; ss += v * v; }
    float m = s / 16.f;
    float var = ss / 16.f - m * m;
    float rstd = rsqrtf(var + EPSF);
    float aa = rstd * g[c], bb = be[c] - m * aa;
    for (int r = 0; r < 16; ++r) {
        float v = h[r * 512 + c] * aa + bb;
        h[r * 512 + c] = v > 0.f ? v : 0.f;
    }
}

// ============================ host ============================
static inline void* wsAlloc(char*& w, size_t bytes) {
    void* p = (void*)w;
    w += (bytes + 255) & ~(size_t)255;
    return p;
}

extern "C" void kernel_launch(void* const* d_in, const int* in_sizes, int n_in,
                              void* d_out, int out_size, void* d_ws, size_t ws_size,
                              hipStream_t stream) {
    (void)in_sizes; (void)n_in; (void)out_size;
    const float* x    = (const float*)d_in[0];
    const float* W1   = (const float*)d_in[2];
    const float* b1   = (const float*)d_in[3];
    const float* g1   = (const float*)d_in[4];
    const float* be1  = (const float*)d_in[5];
    const float* W2   = (const float*)d_in[6];
    const float* b2   = (const float*)d_in[7];
    const float* g2   = (const float*)d_in[8];
    const float* be2  = (const float*)d_in[9];
    const float* W3   = (const float*)d_in[10];
    const float* b3   = (const float*)d_in[11];
    const float* g3   = (const float*)d_in[12];
    const float* be3  = (const float*)d_in[13];
    const float* Wg1  = (const float*)d_in[14];
    const float* bg1  = (const float*)d_in[15];
    const float* gg1  = (const float*)d_in[16];
    const float* beg1 = (const float*)d_in[17];
    const float* Wg2  = (const float*)d_in[18];
    const float* bg2  = (const float*)d_in[19];
    const float* gg2  = (const float*)d_in[20];
    const float* beg2 = (const float*)d_in[21];
    const float* Wn1  = (const float*)d_in[22];
    const float* bn1  = (const float*)d_in[23];
    const float* gn1  = (const float*)d_in[24];
    const float* ben1 = (const float*)d_in[25];
    const float* Wn2  = (const float*)d_in[26];
    const float* bn2  = (const float*)d_in[27];

    char* w = (char*)d_ws;
    float* sq     = (float*)wsAlloc(w, (size_t)NN * 4);
    int*   idx    = (int*)  wsAlloc(w, (size_t)NN * KK * 4);
    float* h0     = (float*)wsAlloc(w, (size_t)NN * 12 * 4);
    float* hA     = (float*)wsAlloc(w, (size_t)NN * 64 * 4);
    float* hB     = (float*)wsAlloc(w, (size_t)NN * 64 * 4);
    float* hg1    = (float*)wsAlloc(w, (size_t)NN * 128 * 4);
    float* ag2    = (float*)wsAlloc(w, (size_t)NN * 128 * 4);
    float* hg2    = (float*)wsAlloc(w, (size_t)NN * 512 * 4);
    float* ps     = (float*)wsAlloc(w, (size_t)131072 * 4);
    float* pss    = (float*)wsAlloc(w, (size_t)131072 * 4);
    float* bnA    = (float*)wsAlloc(w, 512 * 4);
    float* bnS    = (float*)wsAlloc(w, 512 * 4);
    float* pooled = (float*)wsAlloc(w, 16 * 512 * 4);
    float* t16    = (float*)wsAlloc(w, 16 * 512 * 4);
    float* G      = (float*)w;

    size_t used = (size_t)(w - (char*)d_ws);
    size_t avail = (ws_size > used) ? (ws_size - used) : 0;
    int qmax = (int)(avail / ((size_t)BB * PP * 4));
    const int qs_opts[6] = {2048, 1024, 512, 256, 128, 64};
    int QS = 64;
    for (int i = 0; i < 6; ++i) if (qmax >= qs_opts[i]) { QS = qs_opts[i]; break; }

    // ---- local covariance features ----
    knn3_kernel<<<dim3(PP, BB), 256, 0, stream>>>(x, idx);
    cov_kernel<<<NN / 256, 256, 0, stream>>>(x, idx, h0);

    auto dense = [&](const float* in, int K, int C, const float* Wp, const float* bp,
                     const float* gp, const float* bep, float* out) {
        gemm_nn_bias_kernel<<<dim3(C / 64, NN / 64), 256, 0, stream>>>(in, Wp, bp, out, K, C);
        bn_part_kernel<<<256, 256, 0, stream>>>(out, ps, pss, C);
        int R = (C <= 256) ? 256 * (256 / C) : 256;
        bn_final_kernel<<<(C + 255) / 256, 256, 0, stream>>>(ps, pss, gp, bep, bnA, bnS, C, R);
        bn_apply_kernel<<<(int)(((size_t)NN * C) / 256), 256, 0, stream>>>(out, bnA, bnS, C);
    };

    dense(h0, 12, 64, W1, b1, g1, be1, hA);
    dense(hA, 64, 64, W2, b2, g2, be2, hB);
    dense(hB, 64, 64, W3, b3, g3, be3, hA);

    auto knn_feat = [&](const float* f, int D) {
        row_sumsq_kernel<<<NN / 4, 256, 0, stream>>>(f, sq, D);
        for (int p0 = 0; p0 < PP; p0 += QS) {
            gram_kernel<<<dim3(PP / 64, QS / 64, BB), 256, 0, stream>>>(f, G, D, p0, QS);
            knn_sel_kernel<<<dim3(QS, BB), 256, 0, stream>>>(G, sq, idx, p0, QS);
        }
    };

    // ---- graph layer 1 (64-d knn) ----
    knn_feat(hA, 64);
    gathermax_kernel<<<(int)(((size_t)NN * 64) / 256), 256, 0, stream>>>(hA, idx, hB, 64);
    dense(hB, 64, 128, Wg1, bg1, gg1, beg1, hg1);

    // ---- graph layer 2 (128-d knn) ----
    knn_feat(hg1, 128);
    gathermax_kernel<<<(int)(((size_t)NN * 128) / 256), 256, 0, stream>>>(hg1, idx, ag2, 128);
    dense(ag2, 128, 512, Wg2, bg2, gg2, beg2, hg2);

    // ---- global max pool + bottleneck ----
    hipMemsetAsync(pooled, 0, 16 * 512 * 4, stream);
    segmax_kernel<<<dim3(BB, 16), 256, 0, stream>>>(hg2, pooled);
    small_gemm_kernel<<<(16 * 512) / 256, 256, 0, stream>>>(pooled, Wn1, bn1, t16, 512, 512);
    bn16_kernel<<<2, 256, 0, stream>>>(t16, gn1, ben1);
    small_gemm_kernel<<<(16 * 512) / 256, 256, 0, stream>>>(t16, Wn2, bn2, (float*)d_out, 512, 512);
}

// Round 2
// 2749.271 us; speedup vs baseline: 1.2815x; 1.2815x over previous
//
#include <hip/hip_runtime.h>

#define BB 16
#define PP 2048
#define NN 32768   // BB*PP
#define KK 16
#define EPSF 1e-5f

// ============================================================
// Wave-parallel top-16 selection.
// Each lane holds 32 candidate distances d[0..31]; candidate slot j on lane
// `lane` corresponds to global candidate index
//   c(j,lane) = (j>>2)*256 + (j&3) + lane*4
// (i.e. float4-vectorized layout). Selects the 16 smallest (d, c) pairs
// lexicographically (== stable top_k tie semantics), writes global row ids.
// ============================================================
__device__ __forceinline__ void topk16_wave(float (&d)[32], int lane,
                                            int* __restrict__ orow, int base) {
    unsigned consumed = 0;
    int mykeep = 0;
    for (int it = 0; it < KK; ++it) {
        float dmin = 3.4e38f; int jmin = 0;
        #pragma unroll
        for (int j = 0; j < 32; ++j) {
            float dj = ((consumed >> j) & 1u) ? 3.4e38f : d[j];
            if (dj < dmin) { dmin = dj; jmin = j; }   // ties -> lowest j -> lowest c
        }
        float v = dmin;
        int ci = ((jmin >> 2) << 8) + (jmin & 3) + lane * 4;
        #pragma unroll
        for (int off = 32; off; off >>= 1) {
            float v2 = __shfl_xor(v, off);
            int  ci2 = __shfl_xor(ci, off);
            if (v2 < v || (v2 == v && ci2 < ci)) { v = v2; ci = ci2; }
        }
        // all lanes now agree on (v, ci) = global min
        if (lane == ((ci & 255) >> 2))
            consumed |= 1u << (((ci >> 8) << 2) | (ci & 3));
        if (lane == it) mykeep = ci;
    }
    if (lane < KK) orow[lane] = base + mykeep;
}

// ============================ 3-D KNN (wave per query) ============================
// grid: (PP/8, BB), block 256 (4 waves, 2 queries per wave)
__global__ void knn3v2_kernel(const float* __restrict__ x, int* __restrict__ idx) {
    __shared__ float spx[PP], spy[PP], spz[PP], ssq[PP];
    const int b = blockIdx.y, tid = threadIdx.x;
    const float* xc = x + (size_t)b * PP * 3;
    for (int i = tid; i < PP; i += 256) {
        float a = xc[i * 3 + 0], b2 = xc[i * 3 + 1], c2 = xc[i * 3 + 2];
        spx[i] = a; spy[i] = b2; spz[i] = c2;
        ssq[i] = a * a + b2 * b2 + c2 * c2;
    }
    __syncthreads();
    const int lane = tid & 63, w = tid >> 6;
    const float4* px4 = (const float4*)spx;
    const float4* py4 = (const float4*)spy;
    const float4* pz4 = (const float4*)spz;
    const float4* pq4 = (const float4*)ssq;
    for (int qi = 0; qi < 2; ++qi) {
        const int q = blockIdx.x * 8 + w * 2 + qi;
        const float qx = spx[q], qy = spy[q], qz = spz[q], sqQ = ssq[q];
        float d[32];
        #pragma unroll
        for (int jj = 0; jj < 8; ++jj) {
            float4 cx = px4[jj * 64 + lane];
            float4 cy = py4[jj * 64 + lane];
            float4 cz = pz4[jj * 64 + lane];
            float4 cs = pq4[jj * 64 + lane];
            int c0 = jj * 256 + lane * 4;
            float ax[4] = {cx.x, cx.y, cx.z, cx.w};
            float ay[4] = {cy.x, cy.y, cy.z, cy.w};
            float az[4] = {cz.x, cz.y, cz.z, cz.w};
            float as[4] = {cs.x, cs.y, cs.z, cs.w};
            #pragma unroll
            for (int t = 0; t < 4; ++t) {
                float dd = sqQ + as[t] - 2.f * (qx * ax[t] + qy * ay[t] + qz * az[t]);
                if (c0 + t == q) dd += 1e10f;
                d[jj * 4 + t] = dd;
            }
        }
        topk16_wave(d, lane, idx + ((size_t)b * PP + q) * KK, b * PP);
    }
}

// ============================ local covariance -> h0[N,12] ============================
__global__ void cov_kernel(const float* __restrict__ x, const int* __restrict__ idx,
                           float* __restrict__ h0) {
    int p = blockIdx.x * 256 + threadIdx.x;
    if (p >= NN) return;
    const int* ip = idx + (size_t)p * KK;
    float nx[KK], ny[KK], nz[KK];
    float mx = 0.f, my = 0.f, mz = 0.f;
    #pragma unroll
    for (int k = 0; k < KK; ++k) {
        int j = ip[k];
        float a = x[j * 3 + 0], b2 = x[j * 3 + 1], c2 = x[j * 3 + 2];
        nx[k] = a; ny[k] = b2; nz[k] = c2;
        mx += a; my += b2; mz += c2;
    }
    mx *= (1.f / KK); my *= (1.f / KK); mz *= (1.f / KK);
    float cxx = 0, cxy = 0, cxz = 0, cyy = 0, cyz = 0, czz = 0;
    #pragma unroll
    for (int k = 0; k < KK; ++k) {
        float a = nx[k] - mx, b2 = ny[k] - my, c2 = nz[k] - mz;
        cxx += a * a;  cxy += a * b2;  cxz += a * c2;
        cyy += b2 * b2; cyz += b2 * c2; czz += c2 * c2;
    }
    const float s = 1.f / KK;
    float* o = h0 + (size_t)p * 12;
    o[0] = x[p * 3 + 0]; o[1] = x[p * 3 + 1]; o[2] = x[p * 3 + 2];
    o[3] = cxx * s; o[4]  = cxy * s; o[5]  = cxz * s;
    o[6] = cxy * s; o[7]  = cyy * s; o[8]  = cyz * s;
    o[9] = cxz * s; o[10] = cyz * s; o[11] = czz * s;
}

// ============================ tiled GEMM: C[M,Nc] = A[M,K] @ W[K,Nc] + bias ============================
__global__ void gemm_nn_bias_kernel(const float* __restrict__ A, const float* __restrict__ W,
                                    const float* __restrict__ bias, float* __restrict__ C,
                                    int K, int Nc) {
    __shared__ float As[16][68];
    __shared__ float Ws[16][68];
    const int tid = threadIdx.x;
    const int m0 = blockIdx.y * 64, n0 = blockIdx.x * 64;
    const int tx = tid & 15, ty = tid >> 4;
    float acc[4][4] = {};
    for (int k0 = 0; k0 < K; k0 += 16) {
        {
            int kk = tid & 15, mp0 = tid >> 4;
            #pragma unroll
            for (int i = 0; i < 4; ++i) {
                int mp = mp0 + i * 16;
                float v = 0.f;
                if (k0 + kk < K) v = A[(size_t)(m0 + mp) * K + k0 + kk];
                As[kk][mp] = v;
            }
            int nn = tid & 63, kb = tid >> 6;
            #pragma unroll
            for (int i = 0; i < 4; ++i) {
                int kk3 = kb + i * 4;
                float v = 0.f;
                if (k0 + kk3 < K) v = W[(size_t)(k0 + kk3) * Nc + n0 + nn];
                Ws[kk3][nn] = v;
            }
        }
        __syncthreads();
        #pragma unroll
        for (int kk = 0; kk < 16; ++kk) {
            float4 a4 = *(const float4*)&As[kk][ty * 4];
            float4 b4 = *(const float4*)&Ws[kk][tx * 4];
            float av[4] = {a4.x, a4.y, a4.z, a4.w};
            float bv[4] = {b4.x, b4.y, b4.z, b4.w};
            #pragma unroll
            for (int i = 0; i < 4; ++i)
                #pragma unroll
                for (int j = 0; j < 4; ++j)
                    acc[i][j] = fmaf(av[i], bv[j], acc[i][j]);
        }
        __syncthreads();
    }
    float4 bb = *(const float4*)&bias[n0 + tx * 4];
    float bvv[4] = {bb.x, bb.y, bb.z, bb.w};
    #pragma unroll
    for (int i = 0; i < 4; ++i) {
        int m = m0 + ty * 4 + i;
        float4 r;
        r.x = acc[i][0] + bvv[0]; r.y = acc[i][1] + bvv[1];
        r.z = acc[i][2] + bvv[2]; r.w = acc[i][3] + bvv[3];
        *(float4*)&C[(size_t)m * Nc + n0 + tx * 4] = r;
    }
}

// ============================ gram 128x128 tile, 8x8 accumulators ============================
// grid: (PP/128, QS/128, BB), block 256
__global__ void gram128_kernel(const float* __restrict__ f, float* __restrict__ G,
                               int D, int p0, int QS) {
    __shared__ float As[16][132];
    __shared__ float Bs[16][132];
    const int b = blockIdx.z, tid = threadIdx.x;
    const int pm0 = p0 + blockIdx.y * 128, qn0 = blockIdx.x * 128;
    const float* fc = f + (size_t)b * PP * D;
    const int tx = tid & 15, ty = tid >> 4;
    float acc[8][8] = {};
    for (int k0 = 0; k0 < D; k0 += 16) {
        const int kk = tid & 15, r0 = tid >> 4;
        #pragma unroll
        for (int i = 0; i < 8; ++i) {
            int r = r0 + i * 16;
            As[kk][r] = fc[(size_t)(pm0 + r) * D + k0 + kk];
            Bs[kk][r] = fc[(size_t)(qn0 + r) * D + k0 + kk];
        }
        __syncthreads();
        #pragma unroll
        for (int kk2 = 0; kk2 < 16; ++kk2) {
            float4 a0 = *(const float4*)&As[kk2][ty * 8];
            float4 a1 = *(const float4*)&As[kk2][ty * 8 + 4];
            float4 b0 = *(const float4*)&Bs[kk2][tx * 8];
            float4 b1 = *(const float4*)&Bs[kk2][tx * 8 + 4];
            float av[8] = {a0.x, a0.y, a0.z, a0.w, a1.x, a1.y, a1.z, a1.w};
            float bv[8] = {b0.x, b0.y, b0.z, b0.w, b1.x, b1.y, b1.z, b1.w};
            #pragma unroll
            for (int i = 0; i < 8; ++i)
                #pragma unroll
                for (int j = 0; j < 8; ++j)
                    acc[i][j] = fmaf(av[i], bv[j], acc[i][j]);
        }
        __syncthreads();
    }
    float* Gb = G + ((size_t)b * QS + (size_t)(pm0 - p0)) * PP;
    #pragma unroll
    for (int i = 0; i < 8; ++i) {
        float4 r0 = {acc[i][0], acc[i][1], acc[i][2], acc[i][3]};
        float4 r1 = {acc[i][4], acc[i][5], acc[i][6], acc[i][7]};
        float* row = Gb + (size_t)(ty * 8 + i) * PP + qn0 + tx * 8;
        *(float4*)row = r0;
        *(float4*)(row + 4) = r1;
    }
}

// ============================ gram 64x64 (fallback for small QS) ============================
__global__ void gram_kernel(const float* __restrict__ f, float* __restrict__ G,
                            int D, int p0, int QS) {
    __shared__ float As[16][68];
    __shared__ float Bs[16][68];
    const int b = blockIdx.z, tid = threadIdx.x;
    const int pm0 = p0 + blockIdx.y * 64, qn0 = blockIdx.x * 64;
    const float* fc = f + (size_t)b * PP * D;
    const int tx = tid & 15, ty = tid >> 4;
    float acc[4][4] = {};
    for (int k0 = 0; k0 < D; k0 += 16) {
        int kk = tid & 15, r0 = tid >> 4;
        #pragma unroll
        for (int i = 0; i < 4; ++i) {
            As[kk][r0 + i * 16] = fc[(size_t)(pm0 + r0 + i * 16) * D + k0 + kk];
            Bs[kk][r0 + i * 16] = fc[(size_t)(qn0 + r0 + i * 16) * D + k0 + kk];
        }
        __syncthreads();
        #pragma unroll
        for (int kk2 = 0; kk2 < 16; ++kk2) {
            float4 a4 = *(const float4*)&As[kk2][ty * 4];
            float4 b4 = *(const float4*)&Bs[kk2][tx * 4];
            float av[4] = {a4.x, a4.y, a4.z, a4.w};
            float bv[4] = {b4.x, b4.y, b4.z, b4.w};
            #pragma unroll
            for (int i = 0; i < 4; ++i)
                #pragma unroll
                for (int j = 0; j < 4; ++j)
                    acc[i][j] = fmaf(av[i], bv[j], acc[i][j]);
        }
        __syncthreads();
    }
    float* Gb = G + ((size_t)b * QS + (size_t)(pm0 - p0)) * PP;
    #pragma unroll
    for (int i = 0; i < 4; ++i) {
        float4 r = {acc[i][0], acc[i][1], acc[i][2], acc[i][3]};
        *(float4*)&Gb[(size_t)(ty * 4 + i) * PP + qn0 + tx * 4] = r;
    }
}

// ============================ top-16 from gram rows (wave per query) ============================
// grid: (QS/4, BB), block 256
__global__ void knn_sel2_kernel(const float* __restrict__ G, const float* __restrict__ sq,
                                int* __restrict__ idx, int p0, int QS) {
    __shared__ float ssq[PP];
    const int b = blockIdx.y, tid = threadIdx.x;
    const int lane = tid & 63, w = tid >> 6;
    const float* sqc = sq + (size_t)b * PP;
    for (int i = tid; i < PP; i += 256) ssq[i] = sqc[i];
    __syncthreads();
    const int qoff = blockIdx.x * 4 + w;
    const int ql = p0 + qoff;
    const float4* Gr = (const float4*)(G + ((size_t)b * QS + qoff) * PP);
    const float4* sq4 = (const float4*)ssq;
    const float sqQ = ssq[ql];
    float d[32];
    #pragma unroll
    for (int jj = 0; jj < 8; ++jj) {
        float4 g4 = Gr[jj * 64 + lane];
        float4 s4 = sq4[jj * 64 + lane];
        int c0 = jj * 256 + lane * 4;
        float gv[4] = {g4.x, g4.y, g4.z, g4.w};
        float sv[4] = {s4.x, s4.y, s4.z, s4.w};
        #pragma unroll
        for (int t = 0; t < 4; ++t) {
            float dd = sqQ + sv[t] - 2.f * gv[t];
            if (c0 + t == ql) dd += 1e10f;
            d[jj * 4 + t] = dd;
        }
    }
    topk16_wave(d, lane, idx + ((size_t)b * PP + ql) * KK, b * PP);
}

// ============================ row sum of squares ============================
__global__ void row_sumsq_kernel(const float* __restrict__ f, float* __restrict__ sq, int D) {
    const int lane = threadIdx.x & 63;
    const int row = blockIdx.x * 4 + (threadIdx.x >> 6);
    const float* fr = f + (size_t)row * D;
    float s = 0.f;
    for (int d = lane; d < D; d += 64) { float v = fr[d]; s += v * v; }
    #pragma unroll
    for (int off = 32; off; off >>= 1) s += __shfl_down(s, off);
    if (lane == 0) sq[row] = s;
}

// ============================ gather + max over K neighbors ============================
__global__ void gathermax_kernel(const float* __restrict__ f, const int* __restrict__ idx,
                                 float* __restrict__ agg, int C) {
    size_t flat = (size_t)blockIdx.x * 256 + threadIdx.x;
    int c = (int)(flat % C);
    int n = (int)(flat / C);
    const int* ip = idx + (size_t)n * KK;
    float m = -3.4e38f;
    #pragma unroll
    for (int k = 0; k < KK; ++k) {
        float v = f[(size_t)ip[k] * C + c];
        m = fmaxf(m, v);
    }
    agg[flat] = m;
}

// ============================ BN stats (deterministic two-stage) ============================
__global__ void bn_part_kernel(const float* __restrict__ h, float* __restrict__ ps,
                               float* __restrict__ pss, int C) {
    const int blk = blockIdx.x, tid = threadIdx.x;
    const int rows = NN / 256;           // 128
    const int r0 = blk * rows;
    if (C <= 256) {
        int Gn = 256 / C;
        int sub = tid / C, c = tid % C;
        float s = 0.f, ss = 0.f;
        for (int r = r0 + sub; r < r0 + rows; r += Gn) {
            float v = h[(size_t)r * C + c];
            s += v; ss += v * v;
        }
        ps [((size_t)blk * Gn + sub) * C + c] = s;
        pss[((size_t)blk * Gn + sub) * C + c] = ss;
    } else {
        for (int cb = 0; cb < C; cb += 256) {
            int c = cb + tid;
            float s = 0.f, ss = 0.f;
            for (int r = r0; r < r0 + rows; ++r) {
                float v = h[(size_t)r * C + c];
                s += v; ss += v * v;
            }
            ps [(size_t)blk * C + c] = s;
            pss[(size_t)blk * C + c] = ss;
        }
    }
}

__global__ void bn_final_kernel(const float* __restrict__ ps, const float* __restrict__ pss,
                                const float* __restrict__ g, const float* __restrict__ be,
                                float* __restrict__ a, float* __restrict__ bs, int C, int R) {
    int c = blockIdx.x * 256 + threadIdx.x;
    if (c >= C) return;
    float s = 0.f, ss = 0.f;
    for (int r = 0; r < R; ++r) { s += ps[(size_t)r * C + c]; ss += pss[(size_t)r * C + c]; }
    float m = s / (float)NN;
    float v = ss / (float)NN - m * m;
    float rstd = rsqrtf(v + EPSF);
    float aa = rstd * g[c];
    a[c] = aa;
    bs[c] = be[c] - m * aa;
}

__global__ void bn_apply_kernel(float* __restrict__ h, const float* __restrict__ a,
                                const float* __restrict__ bs, int C) {
    size_t flat = (size_t)blockIdx.x * 256 + threadIdx.x;
    int c = (int)(flat % C);
    float v = h[flat] * a[c] + bs[c];
    h[flat] = v > 0.f ? v : 0.f;
}

// ============================ segment max pool ============================
__global__ void segmax_kernel(const float* __restrict__ h, float* __restrict__ pooled) {
    const int b = blockIdx.x, chunk = blockIdx.y, tid = threadIdx.x;
    const int r0 = chunk * 128;
    for (int cb = 0; cb < 512; cb += 256) {
        int c = cb + tid;
        float m = 0.f;
        for (int r = r0; r < r0 + 128; ++r)
            m = fmaxf(m, h[((size_t)b * PP + r) * 512 + c]);
        atomicMax((int*)&pooled[b * 512 + c], __float_as_int(m));
    }
}

// ============================ small GEMM (M=16) ============================
__global__ void small_gemm_kernel(const float* __restrict__ A, const float* __restrict__ W,
                                  const float* __restrict__ bias, float* __restrict__ C,
                                  int K, int Nc) {
    int flat = blockIdx.x * 256 + threadIdx.x;
    int j = flat % Nc, i = flat / Nc;
    float s = bias[j];
    for (int k = 0; k < K; ++k) s = fmaf(A[(size_t)i * K + k], W[(size_t)k * Nc + j], s);
    C[flat] = s;
}

// ============================ BN over 16 rows + ReLU (in place) ============================
__global__ void bn16_kernel(float* __restrict__ h, const float* __restrict__ g,
                            const float* __restrict__ be) {
    int c = blockIdx.x * 256 + threadIdx.x;
    if (c >= 512) return;
    float s = 0.f, ss = 0.f;
    for (int r = 0; r < 16; ++r) { float v = h[r * 512 + c]; s += v; ss += v * v; }
    float m = s / 16.f;
    float var = ss / 16.f - m * m;
    float rstd = rsqrtf(var + EPSF);
    float aa = rstd * g[c], bb = be[c] - m * aa;
    for (int r = 0; r < 16; ++r) {
        float v = h[r * 512 + c] * aa + bb;
        h[r * 512 + c] = v > 0.f ? v : 0.f;
    }
}

// ============================ host ============================
static inline void* wsAlloc(char*& w, size_t bytes) {
    void* p = (void*)w;
    w += (bytes + 255) & ~(size_t)255;
    return p;
}

extern "C" void kernel_launch(void* const* d_in, const int* in_sizes, int n_in,
                              void* d_out, int out_size, void* d_ws, size_t ws_size,
                              hipStream_t stream) {
    (void)in_sizes; (void)n_in; (void)out_size;
    const float* x    = (const float*)d_in[0];
    const float* W1   = (const float*)d_in[2];
    const float* b1   = (const float*)d_in[3];
    const float* g1   = (const float*)d_in[4];
    const float* be1  = (const float*)d_in[5];
    const float* W2   = (const float*)d_in[6];
    const float* b2   = (const float*)d_in[7];
    const float* g2   = (const float*)d_in[8];
    const float* be2  = (const float*)d_in[9];
    const float* W3   = (const float*)d_in[10];
    const float* b3   = (const float*)d_in[11];
    const float* g3   = (const float*)d_in[12];
    const float* be3  = (const float*)d_in[13];
    const float* Wg1  = (const float*)d_in[14];
    const float* bg1  = (const float*)d_in[15];
    const float* gg1  = (const float*)d_in[16];
    const float* beg1 = (const float*)d_in[17];
    const float* Wg2  = (const float*)d_in[18];
    const float* bg2  = (const float*)d_in[19];
    const float* gg2  = (const float*)d_in[20];
    const float* beg2 = (const float*)d_in[21];
    const float* Wn1  = (const float*)d_in[22];
    const float* bn1  = (const float*)d_in[23];
    const float* gn1  = (const float*)d_in[24];
    const float* ben1 = (const float*)d_in[25];
    const float* Wn2  = (const float*)d_in[26];
    const float* bn2  = (const float*)d_in[27];

    char* w = (char*)d_ws;
    float* sq     = (float*)wsAlloc(w, (size_t)NN * 4);
    int*   idx    = (int*)  wsAlloc(w, (size_t)NN * KK * 4);
    float* h0     = (float*)wsAlloc(w, (size_t)NN * 12 * 4);
    float* hA     = (float*)wsAlloc(w, (size_t)NN * 64 * 4);
    float* hB     = (float*)wsAlloc(w, (size_t)NN * 64 * 4);
    float* hg1    = (float*)wsAlloc(w, (size_t)NN * 128 * 4);
    float* ag2    = (float*)wsAlloc(w, (size_t)NN * 128 * 4);
    float* hg2    = (float*)wsAlloc(w, (size_t)NN * 512 * 4);
    float* ps     = (float*)wsAlloc(w, (size_t)131072 * 4);
    float* pss    = (float*)wsAlloc(w, (size_t)131072 * 4);
    float* bnA    = (float*)wsAlloc(w, 512 * 4);
    float* bnS    = (float*)wsAlloc(w, 512 * 4);
    float* pooled = (float*)wsAlloc(w, 16 * 512 * 4);
    float* t16    = (float*)wsAlloc(w, 16 * 512 * 4);
    float* G      = (float*)w;

    size_t used = (size_t)(w - (char*)d_ws);
    size_t avail = (ws_size > used) ? (ws_size - used) : 0;
    int qmax = (int)(avail / ((size_t)BB * PP * 4));
    const int qs_opts[6] = {2048, 1024, 512, 256, 128, 64};
    int QS = 64;
    for (int i = 0; i < 6; ++i) if (qmax >= qs_opts[i]) { QS = qs_opts[i]; break; }

    // ---- local covariance features ----
    knn3v2_kernel<<<dim3(PP / 8, BB), 256, 0, stream>>>(x, idx);
    cov_kernel<<<NN / 256, 256, 0, stream>>>(x, idx, h0);

    auto dense = [&](const float* in, int K, int C, const float* Wp, const float* bp,
                     const float* gp, const float* bep, float* out) {
        gemm_nn_bias_kernel<<<dim3(C / 64, NN / 64), 256, 0, stream>>>(in, Wp, bp, out, K, C);
        bn_part_kernel<<<256, 256, 0, stream>>>(out, ps, pss, C);
        int R = (C <= 256) ? 256 * (256 / C) : 256;
        bn_final_kernel<<<(C + 255) / 256, 256, 0, stream>>>(ps, pss, gp, bep, bnA, bnS, C, R);
        bn_apply_kernel<<<(int)(((size_t)NN * C) / 256), 256, 0, stream>>>(out, bnA, bnS, C);
    };

    dense(h0, 12, 64, W1, b1, g1, be1, hA);
    dense(hA, 64, 64, W2, b2, g2, be2, hB);
    dense(hB, 64, 64, W3, b3, g3, be3, hA);

    auto knn_feat = [&](const float* f, int D) {
        row_sumsq_kernel<<<NN / 4, 256, 0, stream>>>(f, sq, D);
        for (int p0 = 0; p0 < PP; p0 += QS) {
            if (QS >= 128)
                gram128_kernel<<<dim3(PP / 128, QS / 128, BB), 256, 0, stream>>>(f, G, D, p0, QS);
            else
                gram_kernel<<<dim3(PP / 64, QS / 64, BB), 256, 0, stream>>>(f, G, D, p0, QS);
            knn_sel2_kernel<<<dim3(QS / 4, BB), 256, 0, stream>>>(G, sq, idx, p0, QS);
        }
    };

    // ---- graph layer 1 (64-d knn) ----
    knn_feat(hA, 64);
    gathermax_kernel<<<(int)(((size_t)NN * 64) / 256), 256, 0, stream>>>(hA, idx, hB, 64);
    dense(hB, 64, 128, Wg1, bg1, gg1, beg1, hg1);

    // ---- graph layer 2 (128-d knn) ----
    knn_feat(hg1, 128);
    gathermax_kernel<<<(int)(((size_t)NN * 128) / 256), 256, 0, stream>>>(hg1, idx, ag2, 128);
    dense(ag2, 128, 512, Wg2, bg2, gg2, beg2, hg2);

    // ---- global max pool + bottleneck ----
    hipMemsetAsync(pooled, 0, 16 * 512 * 4, stream);
    segmax_kernel<<<dim3(BB, 16), 256, 0, stream>>>(hg2, pooled);
    small_gemm_kernel<<<(16 * 512) / 256, 256, 0, stream>>>(pooled, Wn1, bn1, t16, 512, 512);
    bn16_kernel<<<2, 256, 0, stream>>>(t16, gn1, ben1);
    small_gemm_kernel<<<(16 * 512) / 256, 256, 0, stream>>>(t16, Wn2, bn2, (float*)d_out, 512, 512);
}

// Round 3
// 1656.509 us; speedup vs baseline: 2.1269x; 1.6597x over previous
//
#include <hip/hip_runtime.h>

#define BB 16
#define PP 2048
#define NN 32768   // BB*PP
#define KK 16
#define EPSF 1e-5f

// ============================================================
// Wave-parallel top-16 selection.
// Each lane holds 32 candidate distances d[0..31]; candidate slot j on lane
// `lane` corresponds to global candidate index
//   c(j,lane) = (j>>2)*256 + (j&3) + lane*4
// (i.e. float4-vectorized layout). Selects the 16 smallest (d, c) pairs
// lexicographically (== stable top_k tie semantics), writes global row ids.
// ============================================================
__device__ __forceinline__ void topk16_wave(float (&d)[32], int lane,
                                            int* __restrict__ orow, int base) {
    unsigned consumed = 0;
    int mykeep = 0;
    for (int it = 0; it < KK; ++it) {
        float dmin = 3.4e38f; int jmin = 0;
        #pragma unroll
        for (int j = 0; j < 32; ++j) {
            float dj = ((consumed >> j) & 1u) ? 3.4e38f : d[j];
            if (dj < dmin) { dmin = dj; jmin = j; }   // ties -> lowest j -> lowest c
        }
        float v = dmin;
        int ci = ((jmin >> 2) << 8) + (jmin & 3) + lane * 4;
        #pragma unroll
        for (int off = 32; off; off >>= 1) {
            float v2 = __shfl_xor(v, off);
            int  ci2 = __shfl_xor(ci, off);
            if (v2 < v || (v2 == v && ci2 < ci)) { v = v2; ci = ci2; }
        }
        // all lanes now agree on (v, ci) = global min
        if (lane == ((ci & 255) >> 2))
            consumed |= 1u << (((ci >> 8) << 2) | (ci & 3));
        if (lane == it) mykeep = ci;
    }
    if (lane < KK) orow[lane] = base + mykeep;
}

// ============================ 3-D KNN (wave per query) ============================
// grid: (PP/8, BB), block 256 (4 waves, 2 queries per wave)
__global__ void knn3v2_kernel(const float* __restrict__ x, int* __restrict__ idx) {
    __shared__ float spx[PP], spy[PP], spz[PP], ssq[PP];
    const int b = blockIdx.y, tid = threadIdx.x;
    const float* xc = x + (size_t)b * PP * 3;
    for (int i = tid; i < PP; i += 256) {
        float a = xc[i * 3 + 0], b2 = xc[i * 3 + 1], c2 = xc[i * 3 + 2];
        spx[i] = a; spy[i] = b2; spz[i] = c2;
        ssq[i] = a * a + b2 * b2 + c2 * c2;
    }
    __syncthreads();
    const int lane = tid & 63, w = tid >> 6;
    const float4* px4 = (const float4*)spx;
    const float4* py4 = (const float4*)spy;
    const float4* pz4 = (const float4*)spz;
    const float4* pq4 = (const float4*)ssq;
    for (int qi = 0; qi < 2; ++qi) {
        const int q = blockIdx.x * 8 + w * 2 + qi;
        const float qx = spx[q], qy = spy[q], qz = spz[q], sqQ = ssq[q];
        float d[32];
        #pragma unroll
        for (int jj = 0; jj < 8; ++jj) {
            float4 cx = px4[jj * 64 + lane];
            float4 cy = py4[jj * 64 + lane];
            float4 cz = pz4[jj * 64 + lane];
            float4 cs = pq4[jj * 64 + lane];
            int c0 = jj * 256 + lane * 4;
            float ax[4] = {cx.x, cx.y, cx.z, cx.w};
            float ay[4] = {cy.x, cy.y, cy.z, cy.w};
            float az[4] = {cz.x, cz.y, cz.z, cz.w};
            float as[4] = {cs.x, cs.y, cs.z, cs.w};
            #pragma unroll
            for (int t = 0; t < 4; ++t) {
                float dd = sqQ + as[t] - 2.f * (qx * ax[t] + qy * ay[t] + qz * az[t]);
                if (c0 + t == q) dd += 1e10f;
                d[jj * 4 + t] = dd;
            }
        }
        topk16_wave(d, lane, idx + ((size_t)b * PP + q) * KK, b * PP);
    }
}

// ============================ local covariance -> h0[N,12] ============================
__global__ void cov_kernel(const float* __restrict__ x, const int* __restrict__ idx,
                           float* __restrict__ h0) {
    int p = blockIdx.x * 256 + threadIdx.x;
    if (p >= NN) return;
    const int* ip = idx + (size_t)p * KK;
    float nx[KK], ny[KK], nz[KK];
    float mx = 0.f, my = 0.f, mz = 0.f;
    #pragma unroll
    for (int k = 0; k < KK; ++k) {
        int j = ip[k];
        float a = x[j * 3 + 0], b2 = x[j * 3 + 1], c2 = x[j * 3 + 2];
        nx[k] = a; ny[k] = b2; nz[k] = c2;
        mx += a; my += b2; mz += c2;
    }
    mx *= (1.f / KK); my *= (1.f / KK); mz *= (1.f / KK);
    float cxx = 0, cxy = 0, cxz = 0, cyy = 0, cyz = 0, czz = 0;
    #pragma unroll
    for (int k = 0; k < KK; ++k) {
        float a = nx[k] - mx, b2 = ny[k] - my, c2 = nz[k] - mz;
        cxx += a * a;  cxy += a * b2;  cxz += a * c2;
        cyy += b2 * b2; cyz += b2 * c2; czz += c2 * c2;
    }
    const float s = 1.f / KK;
    float* o = h0 + (size_t)p * 12;
    o[0] = x[p * 3 + 0]; o[1] = x[p * 3 + 1]; o[2] = x[p * 3 + 2];
    o[3] = cxx * s; o[4]  = cxy * s; o[5]  = cxz * s;
    o[6] = cxy * s; o[7]  = cyy * s; o[8]  = cyz * s;
    o[9] = cxz * s; o[10] = cyz * s; o[11] = czz * s;
}

// ============================ tiled GEMM: C[M,Nc] = A[M,K] @ W[K,Nc] + bias ============================
__global__ void gemm_nn_bias_kernel(const float* __restrict__ A, const float* __restrict__ W,
                                    const float* __restrict__ bias, float* __restrict__ C,
                                    int K, int Nc) {
    __shared__ float As[16][68];
    __shared__ float Ws[16][68];
    const int tid = threadIdx.x;
    const int m0 = blockIdx.y * 64, n0 = blockIdx.x * 64;
    const int tx = tid & 15, ty = tid >> 4;
    float acc[4][4] = {};
    for (int k0 = 0; k0 < K; k0 += 16) {
        {
            int kk = tid & 15, mp0 = tid >> 4;
            #pragma unroll
            for (int i = 0; i < 4; ++i) {
                int mp = mp0 + i * 16;
                float v = 0.f;
                if (k0 + kk < K) v = A[(size_t)(m0 + mp) * K + k0 + kk];
                As[kk][mp] = v;
            }
            int nn = tid & 63, kb = tid >> 6;
            #pragma unroll
            for (int i = 0; i < 4; ++i) {
                int kk3 = kb + i * 4;
                float v = 0.f;
                if (k0 + kk3 < K) v = W[(size_t)(k0 + kk3) * Nc + n0 + nn];
                Ws[kk3][nn] = v;
            }
        }
        __syncthreads();
        #pragma unroll
        for (int kk = 0; kk < 16; ++kk) {
            float4 a4 = *(const float4*)&As[kk][ty * 4];
            float4 b4 = *(const float4*)&Ws[kk][tx * 4];
            float av[4] = {a4.x, a4.y, a4.z, a4.w};
            float bv[4] = {b4.x, b4.y, b4.z, b4.w};
            #pragma unroll
            for (int i = 0; i < 4; ++i)
                #pragma unroll
                for (int j = 0; j < 4; ++j)
                    acc[i][j] = fmaf(av[i], bv[j], acc[i][j]);
        }
        __syncthreads();
    }
    float4 bb = *(const float4*)&bias[n0 + tx * 4];
    float bvv[4] = {bb.x, bb.y, bb.z, bb.w};
    #pragma unroll
    for (int i = 0; i < 4; ++i) {
        int m = m0 + ty * 4 + i;
        float4 r;
        r.x = acc[i][0] + bvv[0]; r.y = acc[i][1] + bvv[1];
        r.z = acc[i][2] + bvv[2]; r.w = acc[i][3] + bvv[3];
        *(float4*)&C[(size_t)m * Nc + n0 + tx * 4] = r;
    }
}

// ============================ gram 128x128 tile, 8x8 accumulators ============================
// grid: (PP/128, QS/128, BB), block 256
__global__ void gram128_kernel(const float* __restrict__ f, float* __restrict__ G,
                               int D, int p0, int QS) {
    __shared__ float As[16][132];
    __shared__ float Bs[16][132];
    const int b = blockIdx.z, tid = threadIdx.x;
    const int pm0 = p0 + blockIdx.y * 128, qn0 = blockIdx.x * 128;
    const float* fc = f + (size_t)b * PP * D;
    const int tx = tid & 15, ty = tid >> 4;
    float acc[8][8] = {};
    for (int k0 = 0; k0 < D; k0 += 16) {
        const int kk = tid & 15, r0 = tid >> 4;
        #pragma unroll
        for (int i = 0; i < 8; ++i) {
            int r = r0 + i * 16;
            As[kk][r] = fc[(size_t)(pm0 + r) * D + k0 + kk];
            Bs[kk][r] = fc[(size_t)(qn0 + r) * D + k0 + kk];
        }
        __syncthreads();
        #pragma unroll
        for (int kk2 = 0; kk2 < 16; ++kk2) {
            float4 a0 = *(const float4*)&As[kk2][ty * 8];
            float4 a1 = *(const float4*)&As[kk2][ty * 8 + 4];
            float4 b0 = *(const float4*)&Bs[kk2][tx * 8];
            float4 b1 = *(const float4*)&Bs[kk2][tx * 8 + 4];
            float av[8] = {a0.x, a0.y, a0.z, a0.w, a1.x, a1.y, a1.z, a1.w};
            float bv[8] = {b0.x, b0.y, b0.z, b0.w, b1.x, b1.y, b1.z, b1.w};
            #pragma unroll
            for (int i = 0; i < 8; ++i)
                #pragma unroll
                for (int j = 0; j < 8; ++j)
                    acc[i][j] = fmaf(av[i], bv[j], acc[i][j]);
        }
        __syncthreads();
    }
    float* Gb = G + ((size_t)b * QS + (size_t)(pm0 - p0)) * PP;
    #pragma unroll
    for (int i = 0; i < 8; ++i) {
        float4 r0 = {acc[i][0], acc[i][1], acc[i][2], acc[i][3]};
        float4 r1 = {acc[i][4], acc[i][5], acc[i][6], acc[i][7]};
        float* row = Gb + (size_t)(ty * 8 + i) * PP + qn0 + tx * 8;
        *(float4*)row = r0;
        *(float4*)(row + 4) = r1;
    }
}

// ============================ gram 64x64 (fallback for small QS) ============================
__global__ void gram_kernel(const float* __restrict__ f, float* __restrict__ G,
                            int D, int p0, int QS) {
    __shared__ float As[16][68];
    __shared__ float Bs[16][68];
    const int b = blockIdx.z, tid = threadIdx.x;
    const int pm0 = p0 + blockIdx.y * 64, qn0 = blockIdx.x * 64;
    const float* fc = f + (size_t)b * PP * D;
    const int tx = tid & 15, ty = tid >> 4;
    float acc[4][4] = {};
    for (int k0 = 0; k0 < D; k0 += 16) {
        int kk = tid & 15, r0 = tid >> 4;
        #pragma unroll
        for (int i = 0; i < 4; ++i) {
            As[kk][r0 + i * 16] = fc[(size_t)(pm0 + r0 + i * 16) * D + k0 + kk];
            Bs[kk][r0 + i * 16] = fc[(size_t)(qn0 + r0 + i * 16) * D + k0 + kk];
        }
        __syncthreads();
        #pragma unroll
        for (int kk2 = 0; kk2 < 16; ++kk2) {
            float4 a4 = *(const float4*)&As[kk2][ty * 4];
            float4 b4 = *(const float4*)&Bs[kk2][tx * 4];
            float av[4] = {a4.x, a4.y, a4.z, a4.w};
            float bv[4] = {b4.x, b4.y, b4.z, b4.w};
            #pragma unroll
            for (int i = 0; i < 4; ++i)
                #pragma unroll
                for (int j = 0; j < 4; ++j)
                    acc[i][j] = fmaf(av[i], bv[j], acc[i][j]);
        }
        __syncthreads();
    }
    float* Gb = G + ((size_t)b * QS + (size_t)(pm0 - p0)) * PP;
    #pragma unroll
    for (int i = 0; i < 4; ++i) {
        float4 r = {acc[i][0], acc[i][1], acc[i][2], acc[i][3]};
        *(float4*)&Gb[(size_t)(ty * 4 + i) * PP + qn0 + tx * 4] = r;
    }
}

// ============================ top-16 from gram rows (wave per query) ============================
// grid: (QS/4, BB), block 256
__global__ void knn_sel2_kernel(const float* __restrict__ G, const float* __restrict__ sq,
                                int* __restrict__ idx, int p0, int QS) {
    __shared__ float ssq[PP];
    const int b = blockIdx.y, tid = threadIdx.x;
    const int lane = tid & 63, w = tid >> 6;
    const float* sqc = sq + (size_t)b * PP;
    for (int i = tid; i < PP; i += 256) ssq[i] = sqc[i];
    __syncthreads();
    const int qoff = blockIdx.x * 4 + w;
    const int ql = p0 + qoff;
    const float4* Gr = (const float4*)(G + ((size_t)b * QS + qoff) * PP);
    const float4* sq4 = (const float4*)ssq;
    const float sqQ = ssq[ql];
    float d[32];
    #pragma unroll
    for (int jj = 0; jj < 8; ++jj) {
        float4 g4 = Gr[jj * 64 + lane];
        float4 s4 = sq4[jj * 64 + lane];
        int c0 = jj * 256 + lane * 4;
        float gv[4] = {g4.x, g4.y, g4.z, g4.w};
        float sv[4] = {s4.x, s4.y, s4.z, s4.w};
        #pragma unroll
        for (int t = 0; t < 4; ++t) {
            float dd = sqQ + sv[t] - 2.f * gv[t];
            if (c0 + t == ql) dd += 1e10f;
            d[jj * 4 + t] = dd;
        }
    }
    topk16_wave(d, lane, idx + ((size_t)b * PP + ql) * KK, b * PP);
}

// ============================ row sum of squares ============================
__global__ void row_sumsq_kernel(const float* __restrict__ f, float* __restrict__ sq, int D) {
    const int lane = threadIdx.x & 63;
    const int row = blockIdx.x * 4 + (threadIdx.x >> 6);
    const float* fr = f + (size_t)row * D;
    float s = 0.f;
    for (int d = lane; d < D; d += 64) { float v = fr[d]; s += v * v; }
    #pragma unroll
    for (int off = 32; off; off >>= 1) s += __shfl_down(s, off);
    if (lane == 0) sq[row] = s;
}

// ============================ gather + max over K neighbors ============================
__global__ void gathermax_kernel(const float* __restrict__ f, const int* __restrict__ idx,
                                 float* __restrict__ agg, int C) {
    size_t flat = (size_t)blockIdx.x * 256 + threadIdx.x;
    int c = (int)(flat % C);
    int n = (int)(flat / C);
    const int* ip = idx + (size_t)n * KK;
    float m = -3.4e38f;
    #pragma unroll
    for (int k = 0; k < KK; ++k) {
        float v = f[(size_t)ip[k] * C + c];
        m = fmaxf(m, v);
    }
    agg[flat] = m;
}

// ============================ BN stats (deterministic two-stage) ============================
__global__ void bn_part_kernel(const float* __restrict__ h, float* __restrict__ ps,
                               float* __restrict__ pss, int C) {
    const int blk = blockIdx.x, tid = threadIdx.x;
    const int rows = NN / 256;           // 128
    const int r0 = blk * rows;
    if (C <= 256) {
        int Gn = 256 / C;
        int sub = tid / C, c = tid % C;
        float s = 0.f, ss = 0.f;
        for (int r = r0 + sub; r < r0 + rows; r += Gn) {
            float v = h[(size_t)r * C + c];
            s += v; ss += v * v;
        }
        ps [((size_t)blk * Gn + sub) * C + c] = s;
        pss[((size_t)blk * Gn + sub) * C + c] = ss;
    } else {
        for (int cb = 0; cb < C; cb += 256) {
            int c = cb + tid;
            float s = 0.f, ss = 0.f;
            for (int r = r0; r < r0 + rows; ++r) {
                float v = h[(size_t)r * C + c];
                s += v; ss += v * v;
            }
            ps [(size_t)blk * C + c] = s;
            pss[(size_t)blk * C + c] = ss;
        }
    }
}

// Parallel final reduce: one block per column, 256 threads strided over R
// partials, wave shuffle + LDS tree. Deterministic (fixed tree shape).
__global__ void bn_final2_kernel(const float* __restrict__ ps, const float* __restrict__ pss,
                                 const float* __restrict__ g, const float* __restrict__ be,
                                 float* __restrict__ a, float* __restrict__ bs,
                                 int C, int R) {
    const int c = blockIdx.x, tid = threadIdx.x;
    const int lane = tid & 63, wv = tid >> 6;
    __shared__ float sh_s[4], sh_ss[4];
    float s = 0.f, ss = 0.f;
    for (int r = tid; r < R; r += 256) {
        s  += ps [(size_t)r * C + c];
        ss += pss[(size_t)r * C + c];
    }
    #pragma unroll
    for (int off = 32; off; off >>= 1) {
        s  += __shfl_down(s, off);
        ss += __shfl_down(ss, off);
    }
    if (lane == 0) { sh_s[wv] = s; sh_ss[wv] = ss; }
    __syncthreads();
    if (tid == 0) {
        float ts = sh_s[0] + sh_s[1] + sh_s[2] + sh_s[3];
        float tss = sh_ss[0] + sh_ss[1] + sh_ss[2] + sh_ss[3];
        float m = ts / (float)NN;
        float v = tss / (float)NN - m * m;
        float rstd = rsqrtf(v + EPSF);
        float aa = rstd * g[c];
        a[c] = aa;
        bs[c] = be[c] - m * aa;
    }
}

__global__ void bn_apply_kernel(float* __restrict__ h, const float* __restrict__ a,
                                const float* __restrict__ bs, int C) {
    size_t flat = (size_t)blockIdx.x * 256 + threadIdx.x;
    int c = (int)(flat % C);
    float v = h[flat] * a[c] + bs[c];
    h[flat] = v > 0.f ? v : 0.f;
}

// ============================ segment max pool ============================
__global__ void segmax_kernel(const float* __restrict__ h, float* __restrict__ pooled) {
    const int b = blockIdx.x, chunk = blockIdx.y, tid = threadIdx.x;
    const int r0 = chunk * 128;
    for (int cb = 0; cb < 512; cb += 256) {
        int c = cb + tid;
        float m = 0.f;
        for (int r = r0; r < r0 + 128; ++r)
            m = fmaxf(m, h[((size_t)b * PP + r) * 512 + c]);
        atomicMax((int*)&pooled[b * 512 + c], __float_as_int(m));
    }
}

// ============================ small GEMM (M=16) ============================
__global__ void small_gemm_kernel(const float* __restrict__ A, const float* __restrict__ W,
                                  const float* __restrict__ bias, float* __restrict__ C,
                                  int K, int Nc) {
    int flat = blockIdx.x * 256 + threadIdx.x;
    int j = flat % Nc, i = flat / Nc;
    float s = bias[j];
    for (int k = 0; k < K; ++k) s = fmaf(A[(size_t)i * K + k], W[(size_t)k * Nc + j], s);
    C[flat] = s;
}

// ============================ BN over 16 rows + ReLU (in place) ============================
__global__ void bn16_kernel(float* __restrict__ h, const float* __restrict__ g,
                            const float* __restrict__ be) {
    int c = blockIdx.x * 256 + threadIdx.x;
    if (c >= 512) return;
    float s = 0.f, ss = 0.f;
    for (int r = 0; r < 16; ++r) { float v = h[r * 512 + c]; s += v; ss += v * v; }
    float m = s / 16.f;
    float var = ss / 16.f - m * m;
    float rstd = rsqrtf(var + EPSF);
    float aa = rstd * g[c], bb = be[c] - m * aa;
    for (int r = 0; r < 16; ++r) {
        float v = h[r * 512 + c] * aa + bb;
        h[r * 512 + c] = v > 0.f ? v : 0.f;
    }
}

// ============================ host ============================
static inline void* wsAlloc(char*& w, size_t bytes) {
    void* p = (void*)w;
    w += (bytes + 255) & ~(size_t)255;
    return p;
}

extern "C" void kernel_launch(void* const* d_in, const int* in_sizes, int n_in,
                              void* d_out, int out_size, void* d_ws, size_t ws_size,
                              hipStream_t stream) {
    (void)in_sizes; (void)n_in; (void)out_size;
    const float* x    = (const float*)d_in[0];
    const float* W1   = (const float*)d_in[2];
    const float* b1   = (const float*)d_in[3];
    const float* g1   = (const float*)d_in[4];
    const float* be1  = (const float*)d_in[5];
    const float* W2   = (const float*)d_in[6];
    const float* b2   = (const float*)d_in[7];
    const float* g2   = (const float*)d_in[8];
    const float* be2  = (const float*)d_in[9];
    const float* W3   = (const float*)d_in[10];
    const float* b3   = (const float*)d_in[11];
    const float* g3   = (const float*)d_in[12];
    const float* be3  = (const float*)d_in[13];
    const float* Wg1  = (const float*)d_in[14];
    const float* bg1  = (const float*)d_in[15];
    const float* gg1  = (const float*)d_in[16];
    const float* beg1 = (const float*)d_in[17];
    const float* Wg2  = (const float*)d_in[18];
    const float* bg2  = (const float*)d_in[19];
    const float* gg2  = (const float*)d_in[20];
    const float* beg2 = (const float*)d_in[21];
    const float* Wn1  = (const float*)d_in[22];
    const float* bn1  = (const float*)d_in[23];
    const float* gn1  = (const float*)d_in[24];
    const float* ben1 = (const float*)d_in[25];
    const float* Wn2  = (const float*)d_in[26];
    const float* bn2  = (const float*)d_in[27];

    char* w = (char*)d_ws;
    float* sq     = (float*)wsAlloc(w, (size_t)NN * 4);
    int*   idx    = (int*)  wsAlloc(w, (size_t)NN * KK * 4);
    float* h0     = (float*)wsAlloc(w, (size_t)NN * 12 * 4);
    float* hA     = (float*)wsAlloc(w, (size_t)NN * 64 * 4);
    float* hB     = (float*)wsAlloc(w, (size_t)NN * 64 * 4);
    float* hg1    = (float*)wsAlloc(w, (size_t)NN * 128 * 4);
    float* ag2    = (float*)wsAlloc(w, (size_t)NN * 128 * 4);
    float* hg2    = (float*)wsAlloc(w, (size_t)NN * 512 * 4);
    float* ps     = (float*)wsAlloc(w, (size_t)131072 * 4);
    float* pss    = (float*)wsAlloc(w, (size_t)131072 * 4);
    float* bnA    = (float*)wsAlloc(w, 512 * 4);
    float* bnS    = (float*)wsAlloc(w, 512 * 4);
    float* pooled = (float*)wsAlloc(w, 16 * 512 * 4);
    float* t16    = (float*)wsAlloc(w, 16 * 512 * 4);
    float* G      = (float*)w;

    size_t used = (size_t)(w - (char*)d_ws);
    size_t avail = (ws_size > used) ? (ws_size - used) : 0;
    int qmax = (int)(avail / ((size_t)BB * PP * 4));
    const int qs_opts[6] = {2048, 1024, 512, 256, 128, 64};
    int QS = 64;
    for (int i = 0; i < 6; ++i) if (qmax >= qs_opts[i]) { QS = qs_opts[i]; break; }

    // ---- local covariance features ----
    knn3v2_kernel<<<dim3(PP / 8, BB), 256, 0, stream>>>(x, idx);
    cov_kernel<<<NN / 256, 256, 0, stream>>>(x, idx, h0);

    auto dense = [&](const float* in, int K, int C, const float* Wp, const float* bp,
                     const float* gp, const float* bep, float* out) {
        gemm_nn_bias_kernel<<<dim3(C / 64, NN / 64), 256, 0, stream>>>(in, Wp, bp, out, K, C);
        bn_part_kernel<<<256, 256, 0, stream>>>(out, ps, pss, C);
        int R = (C <= 256) ? 256 * (256 / C) : 256;
        bn_final2_kernel<<<C, 256, 0, stream>>>(ps, pss, gp, bep, bnA, bnS, C, R);
        bn_apply_kernel<<<(int)(((size_t)NN * C) / 256), 256, 0, stream>>>(out, bnA, bnS, C);
    };

    dense(h0, 12, 64, W1, b1, g1, be1, hA);
    dense(hA, 64, 64, W2, b2, g2, be2, hB);
    dense(hB, 64, 64, W3, b3, g3, be3, hA);

    auto knn_feat = [&](const float* f, int D) {
        row_sumsq_kernel<<<NN / 4, 256, 0, stream>>>(f, sq, D);
        for (int p0 = 0; p0 < PP; p0 += QS) {
            if (QS >= 128)
                gram128_kernel<<<dim3(PP / 128, QS / 128, BB), 256, 0, stream>>>(f, G, D, p0, QS);
            else
                gram_kernel<<<dim3(PP / 64, QS / 64, BB), 256, 0, stream>>>(f, G, D, p0, QS);
            knn_sel2_kernel<<<dim3(QS / 4, BB), 256, 0, stream>>>(G, sq, idx, p0, QS);
        }
    };

    // ---- graph layer 1 (64-d knn) ----
    knn_feat(hA, 64);
    gathermax_kernel<<<(int)(((size_t)NN * 64) / 256), 256, 0, stream>>>(hA, idx, hB, 64);
    dense(hB, 64, 128, Wg1, bg1, gg1, beg1, hg1);

    // ---- graph layer 2 (128-d knn) ----
    knn_feat(hg1, 128);
    gathermax_kernel<<<(int)(((size_t)NN * 128) / 256), 256, 0, stream>>>(hg1, idx, ag2, 128);
    dense(ag2, 128, 512, Wg2, bg2, gg2, beg2, hg2);

    // ---- global max pool + bottleneck ----
    hipMemsetAsync(pooled, 0, 16 * 512 * 4, stream);
    segmax_kernel<<<dim3(BB, 16), 256, 0, stream>>>(hg2, pooled);
    small_gemm_kernel<<<(16 * 512) / 256, 256, 0, stream>>>(pooled, Wn1, bn1, t16, 512, 512);
    bn16_kernel<<<2, 256, 0, stream>>>(t16, gn1, ben1);
    small_gemm_kernel<<<(16 * 512) / 256, 256, 0, stream>>>(t16, Wn2, bn2, (float*)d_out, 512, 512);
}